// Round 1
// baseline (681.928 us; speedup 1.0000x reference)
//
#include <hip/hip_runtime.h>
#include <cstddef>

// Problem dims (fixed by the reference): input [T=128, B=256, D1=1024] fp32,
// weight [D2=512, D1=1024] fp32. Outputs spk/V/I each [T, B, D2] fp32,
// concatenated flat in d_out.
#define TT 128
#define BB 256
#define D1 1024
#define D2 512
#define SS (BB * D2)        // 131072 elements per timestep slice
#define MM (127 * BB)       // 32512 GEMM rows (t = 0..126)

// alpha = exp(-1/5), beta = exp(-1/10)
#define ALPHA 0.8187307530779818f
#define BETA  0.9048374180359595f

// ---------------- GEMM: C[m][n] = sum_k A[m][k] * W[n][k] -------------------
// A = input rows 0..MM-1 (K-contiguous), W = weight (K-contiguous) -> "TN" gemm,
// both operands coalesce along K. C written into the I-output region shifted by
// one timestep (cur for scan step t lives at I[t]); scan reads then overwrites.
#define BM 128
#define BN 128
#define BK 16
#define LSTR 136  // 128 + 8 pad: keeps 16B alignment for float4 LDS reads

__global__ __launch_bounds__(256) void gemm_f32(const float* __restrict__ A,
                                                const float* __restrict__ W,
                                                float* __restrict__ C) {
    __shared__ float As[BK][LSTR];  // k-major: As[k][m]
    __shared__ float Ws[BK][LSTR];  // k-major: Ws[k][n]

    const int tid = threadIdx.x;
    const int bm = blockIdx.x * BM;
    const int bn = blockIdx.y * BN;
    const int tx = tid & 15;   // -> n micro-tile
    const int ty = tid >> 4;   // -> m micro-tile
    // staging assignment: 4 threads per row, each thread a float4 k-chunk,
    // rows lrow and lrow+64
    const int lrow = tid >> 2;        // 0..63
    const int lcol = (tid & 3) << 2;  // 0,4,8,12

    const float* Aptr = A + (size_t)(bm + lrow) * D1 + lcol;
    const float* Wptr = W + (size_t)(bn + lrow) * D1 + lcol;

    float acc[8][8];
#pragma unroll
    for (int i = 0; i < 8; ++i)
#pragma unroll
        for (int j = 0; j < 8; ++j) acc[i][j] = 0.0f;

    for (int k0 = 0; k0 < D1; k0 += BK) {
        float4 a0 = *(const float4*)(Aptr + k0);
        float4 a1 = *(const float4*)(Aptr + k0 + (size_t)64 * D1);
        float4 w0 = *(const float4*)(Wptr + k0);
        float4 w1 = *(const float4*)(Wptr + k0 + (size_t)64 * D1);

        __syncthreads();  // previous tile's compute reads must finish
        As[lcol + 0][lrow] = a0.x;
        As[lcol + 1][lrow] = a0.y;
        As[lcol + 2][lrow] = a0.z;
        As[lcol + 3][lrow] = a0.w;
        As[lcol + 0][lrow + 64] = a1.x;
        As[lcol + 1][lrow + 64] = a1.y;
        As[lcol + 2][lrow + 64] = a1.z;
        As[lcol + 3][lrow + 64] = a1.w;
        Ws[lcol + 0][lrow] = w0.x;
        Ws[lcol + 1][lrow] = w0.y;
        Ws[lcol + 2][lrow] = w0.z;
        Ws[lcol + 3][lrow] = w0.w;
        Ws[lcol + 0][lrow + 64] = w1.x;
        Ws[lcol + 1][lrow + 64] = w1.y;
        Ws[lcol + 2][lrow + 64] = w1.z;
        Ws[lcol + 3][lrow + 64] = w1.w;
        __syncthreads();

#pragma unroll
        for (int kk = 0; kk < BK; ++kk) {
            float a[8], b[8];
            *(float4*)&a[0] = *(const float4*)&As[kk][ty * 8];
            *(float4*)&a[4] = *(const float4*)&As[kk][ty * 8 + 4];
            *(float4*)&b[0] = *(const float4*)&Ws[kk][tx * 8];
            *(float4*)&b[4] = *(const float4*)&Ws[kk][tx * 8 + 4];
#pragma unroll
            for (int i = 0; i < 8; ++i)
#pragma unroll
                for (int j = 0; j < 8; ++j) acc[i][j] += a[i] * b[j];
        }
    }

    // epilogue: coalesced float4 stores
#pragma unroll
    for (int i = 0; i < 8; ++i) {
        const size_t m = (size_t)(bm + ty * 8 + i);
        float4 v0 = make_float4(acc[i][0], acc[i][1], acc[i][2], acc[i][3]);
        float4 v1 = make_float4(acc[i][4], acc[i][5], acc[i][6], acc[i][7]);
        *(float4*)&C[m * D2 + bn + tx * 8] = v0;
        *(float4*)&C[m * D2 + bn + tx * 8 + 4] = v1;
    }
}

// ---------------- Scan: sequential over t, parallel over (b, d2) ------------
// d_out layout: spk [TT,SS] | V [TT,SS] | I [TT,SS].
// GEMM has written cur for step t at I + t*SS. Each thread owns one column:
// read c, update (syn, mem), overwrite I[t], write spk[t], V[t]. t=0 zeros.
__global__ __launch_bounds__(256) void scan_kernel(float* __restrict__ out) {
    const int j = blockIdx.x * blockDim.x + threadIdx.x;  // 0..SS-1
    float* __restrict__ spk = out;
    float* __restrict__ V = out + (size_t)TT * SS;
    float* __restrict__ I = out + (size_t)2 * TT * SS;

    spk[j] = 0.0f;
    V[j] = 0.0f;
    I[j] = 0.0f;

    float syn = 0.0f, mem = 0.0f;
    for (int t = 1; t < TT; ++t) {
        const size_t idx = (size_t)t * SS + j;
        const float c = I[idx];
        const float reset = (mem > 1.0f) ? 1.0f : 0.0f;
        syn = ALPHA * syn + c;
        mem = (BETA * mem + syn) * (1.0f - reset);
        spk[idx] = (mem > 1.0f) ? 1.0f : 0.0f;
        V[idx] = mem;
        I[idx] = syn;
    }
}

extern "C" void kernel_launch(void* const* d_in, const int* in_sizes, int n_in,
                              void* d_out, int out_size, void* d_ws, size_t ws_size,
                              hipStream_t stream) {
    const float* input = (const float*)d_in[0];   // [128,256,1024]
    const float* weight = (const float*)d_in[1];  // [512,1024]
    float* out = (float*)d_out;

    // cur for scan step t (1..127) goes at I-region + t*SS:
    // C[m*D2+n] with m=(t-1)*BB+b  ->  I + SS + m*D2 + n
    float* Cdst = out + (size_t)2 * TT * SS + SS;

    gemm_f32<<<dim3(MM / BM, D2 / BN), dim3(256), 0, stream>>>(input, weight, Cdst);
    scan_kernel<<<dim3(SS / 256), dim3(256), 0, stream>>>(out);
}

// Round 2
// 406.492 us; speedup vs baseline: 1.6776x; 1.6776x over previous
//
#include <hip/hip_runtime.h>
#include <cstddef>

// Dims fixed by the reference: input [T=128, B=256, D1=1024] fp32,
// weight [D2=512, D1=1024] fp32. Outputs spk/V/I each [T,B,D2] fp32 concat.
#define TT 128
#define BB 256
#define D1 1024
#define D2 512
#define SS (BB * D2)      // 131072 elems per timestep slice
#define MM (127 * BB)     // 32512 GEMM rows

#define ALPHA 0.8187307530779818f
#define BETA  0.9048374180359595f

typedef _Float16 half8 __attribute__((ext_vector_type(8)));
typedef _Float16 half4v __attribute__((ext_vector_type(4)));
typedef float floatx16 __attribute__((ext_vector_type(16)));

// ---------------------------------------------------------------------------
// W pre-convert: fp32 -> f16 hi + f16 lo*2048 planes (split-f16 trick).
// Planes live in the spk region of d_out (slices 1..4), read by gemm, then
// overwritten by scan afterwards.
// ---------------------------------------------------------------------------
__global__ __launch_bounds__(256) void convert_w(const float* __restrict__ W,
                                                 _Float16* __restrict__ Whi,
                                                 _Float16* __restrict__ Wlo) {
    const int i = (blockIdx.x * 256 + threadIdx.x) * 4;
    float4 w = *(const float4*)(W + i);
    half4v hi, lo;
    hi.x = (_Float16)w.x; lo.x = (_Float16)((w.x - (float)hi.x) * 2048.0f);
    hi.y = (_Float16)w.y; lo.y = (_Float16)((w.y - (float)hi.y) * 2048.0f);
    hi.z = (_Float16)w.z; lo.z = (_Float16)((w.z - (float)hi.z) * 2048.0f);
    hi.w = (_Float16)w.w; lo.w = (_Float16)((w.w - (float)hi.w) * 2048.0f);
    *(half4v*)(Whi + i) = hi;
    *(half4v*)(Wlo + i) = lo;
}

// ---------------------------------------------------------------------------
// Split-f16 MFMA GEMM: C[m][n] = sum_k A[m][k]*W[n][k], fp32-level accuracy.
// C = (hiA*hiB) + 2^-11 * (hiA*loB + loA*hiB); lo terms pre-scaled by 2048.
// Tile BM=64 x BN=256 x BK=32, 256 threads (4 waves), wave-tile 64x64 as
// 2x2 of mfma_f32_32x32x16_f16. A converted fp32->hi/lo during staging.
// LDS row stride 48 f16 (96B): wave64 b128 frag reads spread evenly over all
// 32 banks -> 8-cyc minimum, no conflicts.
// ---------------------------------------------------------------------------
#define BM 64
#define BN 256
#define BK 32
#define LDH 48

__global__ __launch_bounds__(256, 2) void gemm_mfma(const float* __restrict__ A,
                                                    const _Float16* __restrict__ Whi,
                                                    const _Float16* __restrict__ Wlo,
                                                    float* __restrict__ C) {
    __shared__ _Float16 Ah[BM * LDH];
    __shared__ _Float16 Al[BM * LDH];
    __shared__ _Float16 Wh[BN * LDH];
    __shared__ _Float16 Wl[BN * LDH];

    const int tid = threadIdx.x;
    const int lane = tid & 63;
    const int wv = tid >> 6;          // wave 0..3 -> n-offset wv*64
    const int bm = blockIdx.x * BM;
    const int bn = blockIdx.y * BN;

    // staging map: 4 threads per row, 8 elems (16B f16) per thread
    const int arow = tid >> 2;        // 0..63
    const int kch = (tid & 3) * 8;    // 0,8,16,24

    const int m_ = lane & 31;         // MFMA m (or n) index
    const int q = lane >> 5;          // k-quad

    floatx16 accm[2][2], accl[2][2];
#pragma unroll
    for (int i = 0; i < 2; ++i)
#pragma unroll
        for (int j = 0; j < 2; ++j) {
            accm[i][j] = (floatx16)0.0f;
            accl[i][j] = (floatx16)0.0f;
        }

    const float* Abase = A + (size_t)(bm + arow) * D1 + kch;

    for (int k0 = 0; k0 < D1; k0 += BK) {
        // ---- global loads (before barrier) ----
        float4 a0 = *(const float4*)(Abase + k0);
        float4 a1 = *(const float4*)(Abase + k0 + 4);
        half8 wh[4], wl[4];
#pragma unroll
        for (int p = 0; p < 4; ++p) {
            const int wr = bn + p * 64 + arow;
            wh[p] = *(const half8*)(Whi + wr * D1 + k0 + kch);
            wl[p] = *(const half8*)(Wlo + wr * D1 + k0 + kch);
        }

        __syncthreads();  // previous tile's LDS reads done

        // ---- convert A to hi/lo f16 and stage ----
        float av[8] = {a0.x, a0.y, a0.z, a0.w, a1.x, a1.y, a1.z, a1.w};
        half8 ah, al;
#pragma unroll
        for (int j = 0; j < 8; ++j) {
            _Float16 h = (_Float16)av[j];
            ah[j] = h;
            al[j] = (_Float16)((av[j] - (float)h) * 2048.0f);
        }
        *(half8*)&Ah[arow * LDH + kch] = ah;
        *(half8*)&Al[arow * LDH + kch] = al;
#pragma unroll
        for (int p = 0; p < 4; ++p) {
            *(half8*)&Wh[(p * 64 + arow) * LDH + kch] = wh[p];
            *(half8*)&Wl[(p * 64 + arow) * LDH + kch] = wl[p];
        }
        __syncthreads();

        // ---- MFMA: 2 k-steps of 16 ----
#pragma unroll
        for (int kk = 0; kk < BK; kk += 16) {
            const int ko = kk + q * 8;
            half8 a_hi[2], a_lo[2], b_hi[2], b_lo[2];
#pragma unroll
            for (int mb = 0; mb < 2; ++mb) {
                a_hi[mb] = *(const half8*)&Ah[(mb * 32 + m_) * LDH + ko];
                a_lo[mb] = *(const half8*)&Al[(mb * 32 + m_) * LDH + ko];
            }
#pragma unroll
            for (int nb = 0; nb < 2; ++nb) {
                b_hi[nb] = *(const half8*)&Wh[(wv * 64 + nb * 32 + m_) * LDH + ko];
                b_lo[nb] = *(const half8*)&Wl[(wv * 64 + nb * 32 + m_) * LDH + ko];
            }
#pragma unroll
            for (int mb = 0; mb < 2; ++mb)
#pragma unroll
                for (int nb = 0; nb < 2; ++nb) {
                    accm[mb][nb] = __builtin_amdgcn_mfma_f32_32x32x16_f16(
                        a_hi[mb], b_hi[nb], accm[mb][nb], 0, 0, 0);
                    accl[mb][nb] = __builtin_amdgcn_mfma_f32_32x32x16_f16(
                        a_hi[mb], b_lo[nb], accl[mb][nb], 0, 0, 0);
                    accl[mb][nb] = __builtin_amdgcn_mfma_f32_32x32x16_f16(
                        a_lo[mb], b_hi[nb], accl[mb][nb], 0, 0, 0);
                }
        }
    }

    // ---- epilogue: C/D layout col=lane&31, row=(reg&3)+8*(reg>>2)+4*q ----
#pragma unroll
    for (int mb = 0; mb < 2; ++mb)
#pragma unroll
        for (int nb = 0; nb < 2; ++nb) {
            const int n = bn + wv * 64 + nb * 32 + m_;
#pragma unroll
            for (int reg = 0; reg < 16; ++reg) {
                const int row = (reg & 3) + 8 * (reg >> 2) + 4 * q;
                const int m = bm + mb * 32 + row;
                C[m * D2 + n] = accm[mb][nb][reg] + accl[mb][nb][reg] * (1.0f / 2048.0f);
            }
        }
}

// ---------------------------------------------------------------------------
// Scan: sequential in t, parallel over (b,d2). Manual 4-deep load pipeline:
// next group's cur loads are issued (in source order) BEFORE current group's
// stores, keeping 4 loads in flight per wave -> ~32 per CU.
// ---------------------------------------------------------------------------
__global__ __launch_bounds__(256) void scan_kernel(float* __restrict__ out) {
    const int j = blockIdx.x * 256 + threadIdx.x;
    float* spk = out;
    float* V = out + TT * SS;
    float* I = out + 2 * TT * SS;

    spk[j] = 0.0f;
    V[j] = 0.0f;
    I[j] = 0.0f;

    float syn = 0.0f, mem = 0.0f;

#define STEP(tt, cc)                                     \
    {                                                    \
        const float reset = (mem > 1.0f) ? 1.0f : 0.0f;  \
        syn = ALPHA * syn + (cc);                        \
        mem = (BETA * mem + syn) * (1.0f - reset);       \
        const int idx = (tt) * SS + j;                   \
        spk[idx] = (mem > 1.0f) ? 1.0f : 0.0f;           \
        V[idx] = mem;                                    \
        I[idx] = syn;                                    \
    }

    float c0 = I[1 * SS + j];
    float c1 = I[2 * SS + j];
    float c2 = I[3 * SS + j];
    float c3 = I[4 * SS + j];

    int t = 1;
    for (; t <= 117; t += 4) {
        // prefetch next group first (source order => issues before stores)
        const float n0 = I[(t + 4) * SS + j];
        const float n1 = I[(t + 5) * SS + j];
        const float n2 = I[(t + 6) * SS + j];
        const float n3 = I[(t + 7) * SS + j];
        STEP(t + 0, c0);
        STEP(t + 1, c1);
        STEP(t + 2, c2);
        STEP(t + 3, c3);
        c0 = n0; c1 = n1; c2 = n2; c3 = n3;
    }
    // t == 121; c0..c3 hold cur for 121..124
    {
        const float n0 = I[125 * SS + j];
        const float n1 = I[126 * SS + j];
        const float n2 = I[127 * SS + j];
        STEP(121, c0);
        STEP(122, c1);
        STEP(123, c2);
        STEP(124, c3);
        STEP(125, n0);
        STEP(126, n1);
        STEP(127, n2);
    }
#undef STEP
}

extern "C" void kernel_launch(void* const* d_in, const int* in_sizes, int n_in,
                              void* d_out, int out_size, void* d_ws, size_t ws_size,
                              hipStream_t stream) {
    const float* input = (const float*)d_in[0];   // [128,256,1024]
    const float* weight = (const float*)d_in[1];  // [512,1024]
    float* out = (float*)d_out;

    // f16 hi/lo W planes stashed in spk slices 1..4 (2 MB); gemm reads them,
    // scan overwrites them afterwards.
    _Float16* Whi = (_Float16*)(out + SS);
    _Float16* Wlo = Whi + (size_t)D2 * D1;

    // cur for scan step t at I-region slice t (shift by one slice)
    float* Cdst = out + (size_t)2 * TT * SS + SS;

    convert_w<<<dim3((D2 * D1 / 4) / 256), dim3(256), 0, stream>>>(weight, Whi, Wlo);
    gemm_mfma<<<dim3(MM / BM, D2 / BN), dim3(256), 0, stream>>>(input, Whi, Wlo, Cdst);
    scan_kernel<<<dim3(SS / 256), dim3(256), 0, stream>>>(out);
}